// Round 1
// baseline (164.956 us; speedup 1.0000x reference)
//
#include <hip/hip_runtime.h>

// HandcraftedPodExtractor: 3D cell binning + normalized feature vector.
// Input  x: (64, 65536, 6) fp32  [pos(3) | ori(3)] interleaved per point.
// Output  : (64, 640) fp32.
//
// R11 = R6/R10 + u64-packed LDS atomics in k_bin (10 x ds_add_u32 ->
// 5 x ds_add_u64 per point). Theory: DS atomics are instruction-issue
// bound (m134: ds_read_b32 5.8 cyc/instr >> 2-cyc bank bound), so
// halving the instruction count halves the atomic phase (~9-10us -> ~5).
// Packing: each u64 holds two 32-bit fields; all signed fields carry a
// per-add bias of 2^18 so fields stay nonnegative and no borrow/carry
// ever crosses the 32-bit boundary. Bounds: worst case 256 adds per
// copy-slot per cell, each field value < 2^19 -> sum < 2^27 << 2^31;
// cross-copy sum over 16 copies < 2^31. Bias removed exactly at flush
// (bias * exact count). max|ori| ~ 5.7 over 12.6M normals -> max
// |cov*2^12| ~ 134K < BIAS = 262144, margin ~2x.
//
// History: R9 last-block fusion regressed (+26 us: finalize tail raised
// k_bin VGPR -> lost 4 blk/CU); R7/R8 cooperative fusion regressed
// (grid.sync across 8 non-coherent XCD L2s). Two-kernel pipeline wins.
//
// Ceiling accounting: ~107 us harness traffic in timed window (384 MB
// ws-poison @ 59 us + input restore) + k_bbox ~16 (HBM ceiling) +
// k_bin (this change: ~20 -> ~14) + k_final ~4 + gaps ~10.
//
// Fixed-point scales (R3): offsets x2^18, cov x2^12; out err ~1e-4 << 5.9e-3.
// LDS: 64 cells * 5 u64 * 16 copies * 8 B = 40960 B exactly -> 4 blocks/CU.
// Swizzle kk = k ^ (cell & 15): bank-pair index = kk -> 16 copies cover
// all 32 banks.
//
// ws layout:
//   [0,    4096)           : part_max[B*16] as uint bits (nonneg floats)
//   [4096, 4096 + 327680)  : acc[B][640] int64

#define BATCH 64
#define NPTS 65536
#define FEAT 640          // 64 cells * 10 values
#define COPIES 16         // replicated LDS histograms, XOR-swizzled
#define S_OFF 262144.0f   // 2^18
#define S_COV 4096.0f     // 2^12
#define BIAS  262144      // 2^18 per-add bias for packed signed fields

// Packed field layout per cell (f = j >> 1, lo if (j&1)==0):
//   f0: lo = count (j=0), hi = offx (j=1)
//   f1: lo = offy  (j=2), hi = offz (j=3)
//   f2: lo = ox*ox (j=4), hi = ox*oy(j=5)
//   f3: lo = ox*oz (j=6), hi = oy*oy(j=7)
//   f4: lo = oy*oz (j=8), hi = oz*oz(j=9)

__device__ __forceinline__ void bin_point(unsigned long long* h, int k,
                                          float px, float py, float pz,
                                          float ox, float oy, float oz,
                                          float bmax, float inv_thick) {
    float sx = (px + bmax) * inv_thick;
    float sy = (py + bmax) * inv_thick;
    float sz = (pz + bmax) * inv_thick;
    int cx = (int)(sx * 4.0f); cx = cx < 0 ? 0 : (cx > 3 ? 3 : cx);
    int cy = (int)(sy * 4.0f); cy = cy < 0 ? 0 : (cy > 3 ? 3 : cy);
    int cz = (int)(sz * 4.0f); cz = cz < 0 ? 0 : (cz > 3 ? 3 : cz);
    int cell = (cx * 4 + cy) * 4 + cz;
    float offx = sx - (cx * 0.25f + 0.125f);
    float offy = sy - (cy * 0.25f + 0.125f);
    float offz = sz - (cz * 0.25f + 0.125f);
    int qx = __float2int_rn(offx * S_OFF) + BIAS;   // biased, >= 0
    int qy = __float2int_rn(offy * S_OFF) + BIAS;
    int qz = __float2int_rn(offz * S_OFF) + BIAS;
    int c0 = __float2int_rn(ox * ox * S_COV) + BIAS;
    int c1 = __float2int_rn(ox * oy * S_COV) + BIAS;
    int c2 = __float2int_rn(ox * oz * S_COV) + BIAS;
    int c3 = __float2int_rn(oy * oy * S_COV) + BIAS;
    int c4 = __float2int_rn(oy * oz * S_COV) + BIAS;
    int c5 = __float2int_rn(oz * oz * S_COV) + BIAS;
    int kk = k ^ (cell & 15);               // bank-pair de-alias across cells
    unsigned long long* p = h + (size_t)cell * (5 * COPIES) + kk;
    atomicAdd(p + 0 * COPIES, ((unsigned long long)(unsigned)qx << 32) | 1ULL);
    atomicAdd(p + 1 * COPIES, ((unsigned long long)(unsigned)qz << 32) | (unsigned)qy);
    atomicAdd(p + 2 * COPIES, ((unsigned long long)(unsigned)c1 << 32) | (unsigned)c0);
    atomicAdd(p + 3 * COPIES, ((unsigned long long)(unsigned)c3 << 32) | (unsigned)c2);
    atomicAdd(p + 4 * COPIES, ((unsigned long long)(unsigned)c5 << 32) | (unsigned)c4);
}

// Pass 1: per-batch max|pos| -> partial maxes; also zero-init acc.
// grid (16, B) x 256.
__global__ __launch_bounds__(256) void k_bbox(const float* __restrict__ x,
                                              unsigned int* __restrict__ part,
                                              unsigned long long* __restrict__ acc) {
    int b = blockIdx.y;
    int fb = b * 16 + blockIdx.x;             // flat block id 0..1023
    if (threadIdx.x < 40) acc[fb * 40 + threadIdx.x] = 0ULL;

    const float4* F = (const float4*)(x + (size_t)b * NPTS * 6);
    int tid = blockIdx.x * 256 + threadIdx.x;   // 4096 threads per batch
    int tm = tid % 3;
    float m = 0.0f;
    #pragma unroll
    for (int o = 0; o < 2; ++o) {
        #pragma unroll
        for (int u = 0; u < 12; ++u) {
            int it = o * 12 + u;
            float4 v = F[tid + it * 4096];      // unit stride across lanes
            int mm = tm + (u % 3);              // (tm + it) % 3; 12 % 3 == 0
            mm = mm >= 3 ? mm - 3 : mm;
            float ax = fabsf(v.x), ay = fabsf(v.y), az = fabsf(v.z), aw = fabsf(v.w);
            float c0 = fmaxf(fmaxf(ax, ay), az);
            float c1 = fmaxf(az, aw);
            float cand = mm == 0 ? c0 : (mm == 1 ? c1 : ax);
            m = fmaxf(m, cand);
        }
    }
    for (int off = 32; off > 0; off >>= 1) m = fmaxf(m, __shfl_down(m, off, 64));
    __shared__ float s[4];
    if ((threadIdx.x & 63) == 0) s[threadIdx.x >> 6] = m;
    __syncthreads();
    if (threadIdx.x == 0) {
        m = fmaxf(fmaxf(s[0], s[1]), fmaxf(s[2], s[3]));
        part[fb] = __float_as_uint(m);          // plain store, no init needed
    }
}

// Pass 2: packed u64 histogram into 16 XOR-swizzled LDS copies, i64 flush.
// grid (16, B) x 256. LDS = 40960 B -> 4 blocks/CU, no dispatch tail.
__global__ __launch_bounds__(256) void k_bin(const float* __restrict__ x,
                                             const unsigned int* __restrict__ part,
                                             unsigned long long* __restrict__ acc) {
    __shared__ unsigned long long h[64 * 5 * COPIES];   // 40960 B
    for (int i = threadIdx.x; i < 64 * 5 * COPIES; i += 256) h[i] = 0ULL;
    int b = blockIdx.y;
    // reduce the 16 partial maxes (uint compare == float compare for >=0)
    unsigned int um = 0u;
    #pragma unroll
    for (int p = 0; p < 16; ++p) um = um > part[b * 16 + p] ? um : part[b * 16 + p];
    float bmax = __uint_as_float(um);
    float thick = fmaxf(2.0f * bmax, 1e-5f);
    float inv_thick = 1.0f / thick;
    __syncthreads();

    const float4* base = (const float4*)(x + (size_t)b * NPTS * 6);
    int tid = blockIdx.x * 256 + threadIdx.x;   // 4096 threads per batch
    int k = threadIdx.x & (COPIES - 1);
    #pragma unroll
    for (int it = 0; it < 8; ++it) {
        int i = tid + it * 4096;
        float4 f0 = base[3 * i + 0];
        float4 f1 = base[3 * i + 1];
        float4 f2 = base[3 * i + 2];
        bin_point(h, k, f0.x, f0.y, f0.z, f0.w, f1.x, f1.y, bmax, inv_thick);
        bin_point(h, k, f1.z, f1.w, f2.x, f2.y, f2.z, f2.w, bmax, inv_thick);
    }
    __syncthreads();

    // Phase 1: stage per-cell f0 totals (count in lo, biased offx-sum in hi)
    // into copy-slot 0 of f0. Only this thread touches f0 of its cell.
    for (int cell = threadIdx.x; cell < 64; cell += 256) {
        unsigned long long s = 0ULL;
        #pragma unroll
        for (int c = 0; c < COPIES; ++c) s += h[(cell * 5 + 0) * COPIES + c];
        h[cell * 5 * COPIES] = s;
    }
    __syncthreads();

    // Phase 2: 320 workers, one per (cell, field); unpack, de-bias, flush.
    for (int w = threadIdx.x; w < 320; w += 256) {
        int cell = w / 5, f = w - cell * 5;
        unsigned long long sc = h[cell * 5 * COPIES];       // staged f0 total
        long long cnt = (long long)(sc & 0xffffffffULL);    // exact count
        unsigned long long s;
        if (f == 0) {
            s = sc;
        } else {
            s = 0ULL;
            #pragma unroll
            for (int c = 0; c < COPIES; ++c) s += h[(cell * 5 + f) * COPIES + c];
        }
        long long lo = (long long)(s & 0xffffffffULL);
        long long hi = (long long)(s >> 32);
        long long bsub = (long long)BIAS * cnt;
        long long outLo = (f == 0) ? cnt : (lo - bsub);
        long long outHi = hi - bsub;
        atomicAdd(&acc[b * FEAT + cell * 10 + 2 * f + 0], (unsigned long long)outLo);
        atomicAdd(&acc[b * FEAT + cell * 10 + 2 * f + 1], (unsigned long long)outHi);
    }
}

// Pass 3: features + L2 normalize. grid B x 640 (one thread per feature).
__global__ __launch_bounds__(640) void k_final(const unsigned long long* __restrict__ acc,
                                               float* __restrict__ out) {
    int b = blockIdx.x;
    int t = threadIdx.x;           // 0..639
    int cell = t / 10, j = t - cell * 10;
    long long ni = (long long)acc[b * FEAT + cell * 10];   // exact count
    long long vi = (long long)acc[b * FEAT + t];
    float n = (float)ni;
    float fc = fmaxf(n, 1.0f);
    float up = 1.0f / sqrtf(fc);
    float val;
    if (j == 0)      val = 0.001f * n * up;
    else if (j < 4)  val = ((float)vi * (1.0f / S_OFF)) * up;
    else             val = ((float)vi * (1.0f / S_COV)) / fc;

    __shared__ float red[12];
    float s = val * val;
    for (int off = 32; off > 0; off >>= 1) s += __shfl_down(s, off, 64);
    if ((t & 63) == 0) red[t >> 6] = s;
    __syncthreads();
    if (t == 0) {
        float tot = 0.0f;
        #pragma unroll
        for (int w = 0; w < 10; ++w) tot += red[w];
        red[10] = fmaxf(sqrtf(tot), 1e-12f);
    }
    __syncthreads();
    out[b * FEAT + t] = val / red[10];
}

extern "C" void kernel_launch(void* const* d_in, const int* in_sizes, int n_in,
                              void* d_out, int out_size, void* d_ws, size_t ws_size,
                              hipStream_t stream) {
    const float* x = (const float*)d_in[0];
    float* out = (float*)d_out;
    unsigned int* part = (unsigned int*)d_ws;
    unsigned long long* acc = (unsigned long long*)((char*)d_ws + 4096);

    dim3 grid(16, BATCH);
    k_bbox<<<grid, 256, 0, stream>>>(x, part, acc);
    k_bin<<<grid, 256, 0, stream>>>(x, part, acc);
    k_final<<<BATCH, 640, 0, stream>>>(acc, out);
}